// Round 1
// baseline (376.402 us; speedup 1.0000x reference)
//
#include <hip/hip_runtime.h>
#include <math.h>

#define NB 2
#define NL 2048
#define NK 30
#define NEF 128
#define NEIN 416
#define TE 32

__constant__ int c_PA[24] = {0,2,3,4,1,1,1,1,0,0,0,4,4,3,0,2,3,4,2,3,4,2,3,2};
__constant__ int c_PB[24] = {0,2,3,4,0,2,3,4,2,3,4,2,3,2,1,1,1,1,0,0,0,4,4,3};

// ---------------- kernel 0: atoms5 = [N,Ca,C,O,Cb] per residue ----------------
__global__ void k_atoms(const float* __restrict__ X, float* __restrict__ atoms5)
{
    int idx = blockIdx.x * blockDim.x + threadIdx.x;
    if (idx >= NB * NL) return;
    const float* x = X + (size_t)idx * 12;
    float N[3], Ca[3], C[3], O[3], bv[3], cv[3], av[3];
#pragma unroll
    for (int d = 0; d < 3; d++) { N[d] = x[d]; Ca[d] = x[3+d]; C[d] = x[6+d]; O[d] = x[9+d]; }
#pragma unroll
    for (int d = 0; d < 3; d++) { bv[d] = Ca[d] - N[d]; cv[d] = C[d] - Ca[d]; }
    av[0] = bv[1]*cv[2] - bv[2]*cv[1];
    av[1] = bv[2]*cv[0] - bv[0]*cv[2];
    av[2] = bv[0]*cv[1] - bv[1]*cv[0];
    float* o = atoms5 + (size_t)idx * 15;
#pragma unroll
    for (int d = 0; d < 3; d++) {
        o[d]      = N[d];
        o[3 + d]  = Ca[d];
        o[6 + d]  = C[d];
        o[9 + d]  = O[d];
        o[12 + d] = -0.58273431f*av[d] + 0.56802827f*bv[d] - 0.54067466f*cv[d] + Ca[d];
    }
}

// ---------------- kernel 1: exact top-30 by D_adjust per row ----------------
// One block (256 thr) per (b,i). D computed with round-exact ops to match numpy.
// Tie-break by lower index via packed key (bits(D)<<32)|j ; D>=0 so key>=0.
__global__ __launch_bounds__(256) void k_topk(const float* __restrict__ X,
                                              const float* __restrict__ mask,
                                              float* __restrict__ dnb,
                                              int*   __restrict__ eidx,
                                              float* __restrict__ eidx_f)
{
    int row = blockIdx.x;            // b*NL + i
    int b = row >> 11;
    int i = row & (NL - 1);
    __shared__ float dval[NL];
    __shared__ float redf[4];
    __shared__ long long redk[4];
    __shared__ long long bc_key;
    const float* Xb = X + (size_t)b * NL * 12;
    float cax = Xb[i*12+3], cay = Xb[i*12+4], caz = Xb[i*12+5];
    float mi = mask[row];
    int t = threadIdx.x;

    float dloc[NL/256], m2loc[NL/256];
    float lmax = 0.0f;
#pragma unroll
    for (int r = 0; r < NL/256; r++) {
        int j = t + r*256;
        float dx = __fsub_rn(cax, Xb[j*12+3]);
        float dy = __fsub_rn(cay, Xb[j*12+4]);
        float dz = __fsub_rn(caz, Xb[j*12+5]);
        float s  = __fadd_rn(__fadd_rn(__fmul_rn(dx,dx), __fmul_rn(dy,dy)), __fmul_rn(dz,dz));
        s = __fadd_rn(s, 1e-6f);
        float m2 = __fmul_rn(mi, mask[(size_t)b*NL + j]);
        float d  = __fmul_rn(m2, __fsqrt_rn(s));
        dloc[r] = d; m2loc[r] = m2;
        lmax = fmaxf(lmax, d);
    }
#pragma unroll
    for (int off = 32; off; off >>= 1) lmax = fmaxf(lmax, __shfl_xor(lmax, off));
    if ((t & 63) == 0) redf[t >> 6] = lmax;
    __syncthreads();
    float rowmax = fmaxf(fmaxf(redf[0], redf[1]), fmaxf(redf[2], redf[3]));
#pragma unroll
    for (int r = 0; r < NL/256; r++) {
        int j = t + r*256;
        dval[j] = __fadd_rn(dloc[r], __fmul_rn(__fsub_rn(1.0f, m2loc[r]), rowmax));
    }
    __syncthreads();

    long long last = -1LL;
    for (int sel = 0; sel < NK; sel++) {
        long long best = 0x7fffffffffffffffLL;
#pragma unroll
        for (int r = 0; r < NL/256; r++) {
            int j = t + r*256;
            long long key = (((long long)(int)__float_as_uint(dval[j])) << 32) | (long long)j;
            if (key > last && key < best) best = key;
        }
#pragma unroll
        for (int off = 32; off; off >>= 1) {
            long long o = __shfl_xor(best, off);
            best = (o < best) ? o : best;
        }
        if ((t & 63) == 0) redk[t >> 6] = best;
        __syncthreads();
        if (t == 0) {
            long long k01 = (redk[0] < redk[1]) ? redk[0] : redk[1];
            long long k23 = (redk[2] < redk[3]) ? redk[2] : redk[3];
            long long kk  = (k01 < k23) ? k01 : k23;
            bc_key = kk;
            int j = (int)(kk & 0xffffffffLL);
            float dv = __uint_as_float((unsigned)((unsigned long long)kk >> 32));
            int g = row * NK + sel;
            dnb[g] = dv;
            eidx[g] = j;
            eidx_f[g] = (float)j;
        }
        __syncthreads();
        last = bc_key;
    }
}

// ---------------- kernel 2: fused features + GEMM(416x128) + LayerNorm ----------------
// 32 edges per block. Features stored transposed in LDS: fT[k][edge], stride TE+4=36
// (multiple of 4 for b128 alignment, %32 != 0 to spread banks).
__global__ __launch_bounds__(256) void k_edge(const float* __restrict__ atoms5,
                                              const int*   __restrict__ eidx,
                                              const float* __restrict__ dnb,
                                              const int*   __restrict__ ridx,
                                              const int*   __restrict__ chl,
                                              const float* __restrict__ posW,
                                              const float* __restrict__ posb,
                                              const float* __restrict__ eW,
                                              const float* __restrict__ lns,
                                              const float* __restrict__ lno,
                                              float* __restrict__ Eout)
{
    __shared__ float fT[NEIN][TE + 4];
    int t = threadIdx.x;
    int base = blockIdx.x * TE;

    // ---- phase 1: build features (16 threads per edge; thread handles RBF index s)
    {
        int s = t & 15;
        for (int e = t >> 4; e < TE; e += 16) {
            int g = base + e;
            int b = g / (NL * NK);
            int rem = g - b * (NL * NK);
            int i = rem / NK;
            int gi = b * NL + i;
            int j = eidx[g];
            int gj = b * NL + j;

            int off = ridx[gi] - ridx[gj];
            int ec  = (chl[gi] == chl[gj]) ? 1 : 0;
            int dp  = min(max(off + 32, 0), 64);
            dp = ec ? dp : 65;
            fT[s][e] = posW[dp * 16 + s] + posb[s];

            const float* Ai = atoms5 + (size_t)gi * 15;
            const float* Aj = atoms5 + (size_t)gj * 15;
            float D[25];
            D[0] = dnb[g];
#pragma unroll
            for (int p = 0; p < 24; p++) {
                const float* a  = Ai + c_PA[p] * 3;
                const float* bb = Aj + c_PB[p] * 3;
                float dx = a[0]-bb[0], dy = a[1]-bb[1], dz = a[2]-bb[2];
                D[p+1] = sqrtf(dx*dx + dy*dy + dz*dz + 1e-6f);
            }
            float mu = 2.0f + (float)s * (20.0f / 15.0f);
#pragma unroll
            for (int p = 0; p < 25; p++) {
                float z = (D[p] - mu) * 0.8f;   // /1.25
                fT[16 + p * 16 + s][e] = expf(-(z * z));
            }
        }
    }
    __syncthreads();

    // ---- phase 2: GEMM. thread = (col group cg: 4 cols) x (edge group eg: 4 edges)
    int cg = t & 31;
    int eg = t >> 5;
    const float* wp = eW + cg * 4;
    float acc[4][4];
#pragma unroll
    for (int e = 0; e < 4; e++)
#pragma unroll
        for (int c = 0; c < 4; c++) acc[e][c] = 0.0f;

    for (int k = 0; k < NEIN; k++) {
        float4 w  = *(const float4*)(wp + (size_t)k * NEF);
        float4 fv = *(const float4*)(&fT[k][eg * 4]);
        float fe[4] = {fv.x, fv.y, fv.z, fv.w};
        float wc[4] = {w.x, w.y, w.z, w.w};
#pragma unroll
        for (int e = 0; e < 4; e++)
#pragma unroll
            for (int c = 0; c < 4; c++)
                acc[e][c] = fmaf(fe[e], wc[c], acc[e][c]);
    }

    // ---- phase 3: LayerNorm over 128 cols (spread across the 32 lanes sharing eg)
    float sum[4], ssq[4];
#pragma unroll
    for (int e = 0; e < 4; e++) {
        sum[e] = acc[e][0] + acc[e][1] + acc[e][2] + acc[e][3];
        ssq[e] = acc[e][0]*acc[e][0] + acc[e][1]*acc[e][1]
               + acc[e][2]*acc[e][2] + acc[e][3]*acc[e][3];
    }
#pragma unroll
    for (int off = 1; off < 32; off <<= 1) {
#pragma unroll
        for (int e = 0; e < 4; e++) {
            sum[e] += __shfl_xor(sum[e], off);
            ssq[e] += __shfl_xor(ssq[e], off);
        }
    }
    float4 sc = *(const float4*)(lns + cg * 4);
    float4 of = *(const float4*)(lno + cg * 4);
#pragma unroll
    for (int e = 0; e < 4; e++) {
        int g = base + eg * 4 + e;
        float mu  = sum[e] * (1.0f / 128.0f);
        float var = ssq[e] * (1.0f / 128.0f) - mu * mu;
        float rs  = 1.0f / sqrtf(var + 1e-5f);
        float4 o;
        o.x = sc.x * ((acc[e][0] - mu) * rs) + of.x;
        o.y = sc.y * ((acc[e][1] - mu) * rs) + of.y;
        o.z = sc.z * ((acc[e][2] - mu) * rs) + of.z;
        o.w = sc.w * ((acc[e][3] - mu) * rs) + of.w;
        *(float4*)(Eout + (size_t)g * NEF + cg * 4) = o;
    }
}

extern "C" void kernel_launch(void* const* d_in, const int* in_sizes, int n_in,
                              void* d_out, int out_size, void* d_ws, size_t ws_size,
                              hipStream_t stream)
{
    const float* X    = (const float*)d_in[0];
    const float* mask = (const float*)d_in[1];
    const int*   ridx = (const int*)d_in[2];
    const int*   chl  = (const int*)d_in[3];
    const float* posW = (const float*)d_in[4];
    const float* posb = (const float*)d_in[5];
    const float* eW   = (const float*)d_in[6];
    const float* lns  = (const float*)d_in[7];
    const float* lno  = (const float*)d_in[8];

    float* Eout   = (float*)d_out;                                  // B*L*K*128
    float* eidx_f = Eout + (size_t)NB * NL * NK * NEF;              // B*L*K (as float)

    float* atoms5 = (float*)d_ws;                                   // B*L*15
    float* dnb    = atoms5 + (size_t)NB * NL * 15;                  // B*L*K
    int*   eidx   = (int*)(dnb + (size_t)NB * NL * NK);             // B*L*K

    k_atoms<<<(NB * NL + 255) / 256, 256, 0, stream>>>(X, atoms5);
    k_topk<<<NB * NL, 256, 0, stream>>>(X, mask, dnb, eidx, eidx_f);
    k_edge<<<(NB * NL * NK) / TE, 256, 0, stream>>>(atoms5, eidx, dnb, ridx, chl,
                                                    posW, posb, eW, lns, lno, Eout);
}

// Round 2
// 187.026 us; speedup vs baseline: 2.0126x; 2.0126x over previous
//
#include <hip/hip_runtime.h>
#include <math.h>

#define NB 2
#define NL 2048
#define NK 30
#define NEF 128
#define NEIN 416
#define BM 64            // edges per block in k_edge

typedef _Float16 half8 __attribute__((ext_vector_type(8)));
typedef _Float16 half4 __attribute__((ext_vector_type(4)));
typedef float f32x4 __attribute__((ext_vector_type(4)));

__constant__ int c_PA[24] = {0,2,3,4,1,1,1,1,0,0,0,4,4,3,0,2,3,4,2,3,4,2,3,2};
__constant__ int c_PB[24] = {0,2,3,4,0,2,3,4,2,3,4,2,3,2,1,1,1,1,0,0,0,4,4,3};

// ---------------- kernel 0: atoms5 = [N,Ca,C,O,Cb] per residue ----------------
__global__ void k_atoms(const float* __restrict__ X, float* __restrict__ atoms5)
{
    int idx = blockIdx.x * blockDim.x + threadIdx.x;
    if (idx >= NB * NL) return;
    const float* x = X + (size_t)idx * 12;
    float N[3], Ca[3], C[3], O[3], bv[3], cv[3], av[3];
#pragma unroll
    for (int d = 0; d < 3; d++) { N[d] = x[d]; Ca[d] = x[3+d]; C[d] = x[6+d]; O[d] = x[9+d]; }
#pragma unroll
    for (int d = 0; d < 3; d++) { bv[d] = Ca[d] - N[d]; cv[d] = C[d] - Ca[d]; }
    av[0] = bv[1]*cv[2] - bv[2]*cv[1];
    av[1] = bv[2]*cv[0] - bv[0]*cv[2];
    av[2] = bv[0]*cv[1] - bv[1]*cv[0];
    float* o = atoms5 + (size_t)idx * 15;
#pragma unroll
    for (int d = 0; d < 3; d++) {
        o[d]      = N[d];
        o[3 + d]  = Ca[d];
        o[6 + d]  = C[d];
        o[9 + d]  = O[d];
        o[12 + d] = -0.58273431f*av[d] + 0.56802827f*bv[d] - 0.54067466f*cv[d] + Ca[d];
    }
}

// ---------------- kernel 0b: W (416x128 f32) -> Wt (128x416 f16) ----------------
__global__ void k_wconv(const float* __restrict__ eW, _Float16* __restrict__ Wt)
{
    int idx = blockIdx.x * blockDim.x + threadIdx.x;
    if (idx >= NEIN * NEF) return;
    int k = idx >> 7;
    int c = idx & 127;
    Wt[(size_t)c * NEIN + k] = (_Float16)eW[idx];
}

// ---------------- kernel 1: exact top-30 by D_adjust per row ----------------
__global__ __launch_bounds__(256) void k_topk(const float* __restrict__ X,
                                              const float* __restrict__ mask,
                                              float* __restrict__ dnb,
                                              int*   __restrict__ eidx,
                                              float* __restrict__ eidx_f)
{
    int row = blockIdx.x;            // b*NL + i
    int b = row >> 11;
    int i = row & (NL - 1);
    __shared__ float dval[NL];
    __shared__ float redf[4];
    __shared__ long long redk[4];
    __shared__ long long bc_key;
    const float* Xb = X + (size_t)b * NL * 12;
    float cax = Xb[i*12+3], cay = Xb[i*12+4], caz = Xb[i*12+5];
    float mi = mask[row];
    int t = threadIdx.x;

    float dloc[NL/256], m2loc[NL/256];
    float lmax = 0.0f;
#pragma unroll
    for (int r = 0; r < NL/256; r++) {
        int j = t + r*256;
        float dx = __fsub_rn(cax, Xb[j*12+3]);
        float dy = __fsub_rn(cay, Xb[j*12+4]);
        float dz = __fsub_rn(caz, Xb[j*12+5]);
        float s  = __fadd_rn(__fadd_rn(__fmul_rn(dx,dx), __fmul_rn(dy,dy)), __fmul_rn(dz,dz));
        s = __fadd_rn(s, 1e-6f);
        float m2 = __fmul_rn(mi, mask[(size_t)b*NL + j]);
        float d  = __fmul_rn(m2, __fsqrt_rn(s));
        dloc[r] = d; m2loc[r] = m2;
        lmax = fmaxf(lmax, d);
    }
#pragma unroll
    for (int off = 32; off; off >>= 1) lmax = fmaxf(lmax, __shfl_xor(lmax, off));
    if ((t & 63) == 0) redf[t >> 6] = lmax;
    __syncthreads();
    float rowmax = fmaxf(fmaxf(redf[0], redf[1]), fmaxf(redf[2], redf[3]));
#pragma unroll
    for (int r = 0; r < NL/256; r++) {
        int j = t + r*256;
        dval[j] = __fadd_rn(dloc[r], __fmul_rn(__fsub_rn(1.0f, m2loc[r]), rowmax));
    }
    __syncthreads();

    long long last = -1LL;
    for (int sel = 0; sel < NK; sel++) {
        long long best = 0x7fffffffffffffffLL;
#pragma unroll
        for (int r = 0; r < NL/256; r++) {
            int j = t + r*256;
            long long key = (((long long)(int)__float_as_uint(dval[j])) << 32) | (long long)j;
            if (key > last && key < best) best = key;
        }
#pragma unroll
        for (int off = 32; off; off >>= 1) {
            long long o = __shfl_xor(best, off);
            best = (o < best) ? o : best;
        }
        if ((t & 63) == 0) redk[t >> 6] = best;
        __syncthreads();
        if (t == 0) {
            long long k01 = (redk[0] < redk[1]) ? redk[0] : redk[1];
            long long k23 = (redk[2] < redk[3]) ? redk[2] : redk[3];
            long long kk  = (k01 < k23) ? k01 : k23;
            bc_key = kk;
            int j = (int)(kk & 0xffffffffLL);
            float dv = __uint_as_float((unsigned)((unsigned long long)kk >> 32));
            int g = row * NK + sel;
            dnb[g] = dv;
            eidx[g] = j;
            eidx_f[g] = (float)j;
        }
        __syncthreads();
        last = bc_key;
    }
}

// ---------------- kernel 2: features(f16) + MFMA GEMM + LayerNorm ----------------
// 64 edges per block, 4 waves. fA[64][424] f16 (row stride 848B -> 2-way banks = free).
// Wave w owns edge rows w*16..w*16+15, all 128 cols.
// mfma_f32_16x16x32_f16: A row = lane%16, k = (lane>>4)*8+e ;
//                        B col = lane%16, k = (lane>>4)*8+e ;
//                        C col = lane&15, row = (lane>>4)*4+r  [verified layout]
__global__ __launch_bounds__(256) void k_edge(const float* __restrict__ atoms5,
                                              const int*   __restrict__ eidx,
                                              const float* __restrict__ dnb,
                                              const int*   __restrict__ ridx,
                                              const int*   __restrict__ chl,
                                              const float* __restrict__ posW,
                                              const float* __restrict__ posb,
                                              const _Float16* __restrict__ Wt,
                                              const float* __restrict__ lns,
                                              const float* __restrict__ lno,
                                              float* __restrict__ Eout)
{
    __shared__ __align__(16) _Float16 fA[BM][424];
    int t = threadIdx.x;
    int base = blockIdx.x * BM;

    // ---- phase 1: features. 4 threads per edge; thread q handles s = q*4..q*4+3
    {
        int e = t >> 2;
        int q = t & 3;
        int g = base + e;
        int b = g / (NL * NK);
        int rem = g - b * (NL * NK);
        int i = rem / NK;
        int gi = b * NL + i;
        int j = eidx[g];
        int gj = b * NL + j;

        int off = ridx[gi] - ridx[gj];
        int ec  = (chl[gi] == chl[gj]) ? 1 : 0;
        int dp  = min(max(off + 32, 0), 64);
        dp = ec ? dp : 65;
        half4 pv;
#pragma unroll
        for (int u = 0; u < 4; u++) {
            int s = q * 4 + u;
            pv[u] = (_Float16)(posW[dp * 16 + s] + posb[s]);
        }
        *(half4*)&fA[e][q * 4] = pv;

        const float* Ai = atoms5 + (size_t)gi * 15;
        const float* Aj = atoms5 + (size_t)gj * 15;
        float D[25];
        D[0] = dnb[g];
#pragma unroll
        for (int p = 0; p < 24; p++) {
            const float* a  = Ai + c_PA[p] * 3;
            const float* bb = Aj + c_PB[p] * 3;
            float dx = a[0]-bb[0], dy = a[1]-bb[1], dz = a[2]-bb[2];
            D[p+1] = sqrtf(dx*dx + dy*dy + dz*dz + 1e-6f);
        }
        float mu0 = 2.0f + (float)(q * 4) * (20.0f / 15.0f);
#pragma unroll
        for (int p = 0; p < 25; p++) {
            half4 rv;
#pragma unroll
            for (int u = 0; u < 4; u++) {
                float mu = mu0 + (float)u * (20.0f / 15.0f);
                float z = (D[p] - mu) * 0.8f;
                rv[u] = (_Float16)__expf(-(z * z));
            }
            *(half4*)&fA[e][16 + p * 16 + q * 4] = rv;
        }
    }
    __syncthreads();

    // ---- phase 2: MFMA GEMM
    int w    = t >> 6;
    int lane = t & 63;
    int l16  = lane & 15;
    int g8   = (lane >> 4) * 8;

    f32x4 acc[8];
#pragma unroll
    for (int nt = 0; nt < 8; nt++) acc[nt] = (f32x4){0.f, 0.f, 0.f, 0.f};

    const _Float16* fArow = &fA[w * 16 + l16][0];
    const _Float16* wtb   = Wt + (size_t)l16 * NEIN + g8;

    for (int kt = 0; kt < 13; kt++) {
        half8 a = *(const half8*)(fArow + kt * 32 + g8);
#pragma unroll
        for (int nt = 0; nt < 8; nt++) {
            half8 bf = *(const half8*)(wtb + (size_t)nt * 16 * NEIN + kt * 32);
            acc[nt] = __builtin_amdgcn_mfma_f32_16x16x32_f16(a, bf, acc[nt], 0, 0, 0);
        }
    }

    // ---- phase 3: LayerNorm. Row (lane>>4)*4+r lives in one 16-lane group.
    float sum[4], ssq[4];
#pragma unroll
    for (int r = 0; r < 4; r++) { sum[r] = 0.f; ssq[r] = 0.f; }
#pragma unroll
    for (int nt = 0; nt < 8; nt++)
#pragma unroll
        for (int r = 0; r < 4; r++) {
            float v = acc[nt][r];
            sum[r] += v;
            ssq[r] += v * v;
        }
#pragma unroll
    for (int off = 1; off < 16; off <<= 1)
#pragma unroll
        for (int r = 0; r < 4; r++) {
            sum[r] += __shfl_xor(sum[r], off);
            ssq[r] += __shfl_xor(ssq[r], off);
        }

    float sc[8], of[8];
#pragma unroll
    for (int nt = 0; nt < 8; nt++) {
        sc[nt] = lns[nt * 16 + l16];
        of[nt] = lno[nt * 16 + l16];
    }
#pragma unroll
    for (int r = 0; r < 4; r++) {
        float mu  = sum[r] * (1.0f / 128.0f);
        float var = ssq[r] * (1.0f / 128.0f) - mu * mu;
        float rs  = 1.0f / sqrtf(var + 1e-5f);
        int edge  = base + w * 16 + (lane >> 4) * 4 + r;
        float* op = Eout + (size_t)edge * NEF + l16;
#pragma unroll
        for (int nt = 0; nt < 8; nt++)
            op[nt * 16] = sc[nt] * ((acc[nt][r] - mu) * rs) + of[nt];
    }
}

extern "C" void kernel_launch(void* const* d_in, const int* in_sizes, int n_in,
                              void* d_out, int out_size, void* d_ws, size_t ws_size,
                              hipStream_t stream)
{
    const float* X    = (const float*)d_in[0];
    const float* mask = (const float*)d_in[1];
    const int*   ridx = (const int*)d_in[2];
    const int*   chl  = (const int*)d_in[3];
    const float* posW = (const float*)d_in[4];
    const float* posb = (const float*)d_in[5];
    const float* eW   = (const float*)d_in[6];
    const float* lns  = (const float*)d_in[7];
    const float* lno  = (const float*)d_in[8];

    float* Eout   = (float*)d_out;                                  // B*L*K*128
    float* eidx_f = Eout + (size_t)NB * NL * NK * NEF;              // B*L*K (as float)

    char* ws = (char*)d_ws;
    float*    atoms5 = (float*)ws;                                  // 4096*15 f32
    float*    dnb    = (float*)(ws + 245760);                       // 122880 f32
    int*      eidx   = (int*)(ws + 737280);                         // 122880 i32
    _Float16* Wt     = (_Float16*)(ws + 1228800);                   // 128*416 f16

    k_atoms<<<(NB * NL + 255) / 256, 256, 0, stream>>>(X, atoms5);
    k_wconv<<<(NEIN * NEF + 255) / 256, 256, 0, stream>>>(eW, Wt);
    k_topk<<<NB * NL, 256, 0, stream>>>(X, mask, dnb, eidx, eidx_f);
    k_edge<<<(NB * NL * NK) / BM, 256, 0, stream>>>(atoms5, eidx, dnb, ridx, chl,
                                                    posW, posb, Wt, lns, lno, Eout);
}

// Round 3
// 146.468 us; speedup vs baseline: 2.5699x; 1.2769x over previous
//
#include <hip/hip_runtime.h>
#include <math.h>

#define NB 2
#define NL 2048
#define NK 30
#define NEF 128
#define NEIN 416
#define BM 64            // edges per block in k_edge

typedef _Float16 half8 __attribute__((ext_vector_type(8)));
typedef _Float16 half4 __attribute__((ext_vector_type(4)));
typedef float f32x4 __attribute__((ext_vector_type(4)));

__constant__ int c_PA[24] = {0,2,3,4,1,1,1,1,0,0,0,4,4,3,0,2,3,4,2,3,4,2,3,2};
__constant__ int c_PB[24] = {0,2,3,4,0,2,3,4,2,3,4,2,3,2,1,1,1,1,0,0,0,4,4,3};

// ------- kernel 0: atoms5 = [N,Ca,C,O,Cb]; caw4 = packed (Ca.xyz, mask) -------
__global__ void k_atoms(const float* __restrict__ X, const float* __restrict__ mask,
                        float* __restrict__ atoms5, float4* __restrict__ caw4)
{
    int idx = blockIdx.x * blockDim.x + threadIdx.x;
    if (idx >= NB * NL) return;
    const float* x = X + (size_t)idx * 12;
    float N[3], Ca[3], C[3], O[3], bv[3], cv[3], av[3];
#pragma unroll
    for (int d = 0; d < 3; d++) { N[d] = x[d]; Ca[d] = x[3+d]; C[d] = x[6+d]; O[d] = x[9+d]; }
#pragma unroll
    for (int d = 0; d < 3; d++) { bv[d] = Ca[d] - N[d]; cv[d] = C[d] - Ca[d]; }
    av[0] = bv[1]*cv[2] - bv[2]*cv[1];
    av[1] = bv[2]*cv[0] - bv[0]*cv[2];
    av[2] = bv[0]*cv[1] - bv[1]*cv[0];
    float* o = atoms5 + (size_t)idx * 15;
#pragma unroll
    for (int d = 0; d < 3; d++) {
        o[d]      = N[d];
        o[3 + d]  = Ca[d];
        o[6 + d]  = C[d];
        o[9 + d]  = O[d];
        o[12 + d] = -0.58273431f*av[d] + 0.56802827f*bv[d] - 0.54067466f*cv[d] + Ca[d];
    }
    caw4[idx] = make_float4(Ca[0], Ca[1], Ca[2], mask[idx]);
}

// ---------------- kernel 0b: W (416x128 f32) -> Wt (128x416 f16) ----------------
__global__ void k_wconv(const float* __restrict__ eW, _Float16* __restrict__ Wt)
{
    int idx = blockIdx.x * blockDim.x + threadIdx.x;
    if (idx >= NEIN * NEF) return;
    int k = idx >> 7;
    int c = idx & 127;
    Wt[(size_t)c * NEIN + k] = (_Float16)eW[idx];
}

// ---------------- kernel 1: exact top-30, one WAVE per row ----------------
// Lane holds 32 keys (bits(D_adjust)<<32)|j in regs. 30x {reg scan + shfl min
// butterfly}. No LDS/barriers in the selection loop. Arithmetic uses the same
// __f*_rn chain as before -> bit-identical selection vs the passing kernel.
__global__ __launch_bounds__(256) void k_topk(const float4* __restrict__ caw4,
                                              float* __restrict__ dnb,
                                              int*   __restrict__ eidx,
                                              float* __restrict__ eidx_f)
{
    __shared__ float4 ca[NL];
    int t = threadIdx.x;
    int base = blockIdx.x << 2;          // 4 rows per block (one per wave)
    int b = base >> 11;
    const float4* src = caw4 + (size_t)b * NL;
#pragma unroll
    for (int r = 0; r < NL/256; r++) ca[t + r*256] = src[t + r*256];
    __syncthreads();

    int w = t >> 6, lane = t & 63;
    int row = base + w;
    int i = row & (NL - 1);
    float4 ci = ca[i];
    float mi = ci.w;

    unsigned long long key[32];
    unsigned mflags = 0;                  // bit r: m2 != 0
    float lmax = 0.0f;
#pragma unroll
    for (int r = 0; r < 32; r++) {
        float4 cj = ca[r*64 + lane];
        float dx = __fsub_rn(ci.x, cj.x);
        float dy = __fsub_rn(ci.y, cj.y);
        float dz = __fsub_rn(ci.z, cj.z);
        float s  = __fadd_rn(__fadd_rn(__fmul_rn(dx,dx), __fmul_rn(dy,dy)), __fmul_rn(dz,dz));
        s = __fadd_rn(s, 1e-6f);
        float m2 = __fmul_rn(mi, cj.w);   // binary mask: 0 or 1
        float d  = __fmul_rn(m2, __fsqrt_rn(s));
        lmax = fmaxf(lmax, d);
        mflags |= (m2 != 0.0f) ? (1u << r) : 0u;
        key[r] = ((unsigned long long)__float_as_uint(d) << 32) | (unsigned)(r*64 + lane);
    }
#pragma unroll
    for (int off = 32; off; off >>= 1) lmax = fmaxf(lmax, __shfl_xor(lmax, off));
    // D_adjust: m2==1 -> d + 0*rowmax == d (exact); m2==0 -> 0 + 1*rowmax == rowmax (exact)
    unsigned rmb = __float_as_uint(lmax);
#pragma unroll
    for (int r = 0; r < 32; r++) {
        bool um = (mflags >> r) & 1u;
        unsigned hi = um ? (unsigned)(key[r] >> 32) : rmb;
        key[r] = ((unsigned long long)hi << 32) | (key[r] & 0xffffffffULL);
    }

    long long last = -1LL;
    long long mykey = 0;
    for (int sel = 0; sel < NK; sel++) {
        long long best = 0x7fffffffffffffffLL;
#pragma unroll
        for (int r = 0; r < 32; r++) {
            long long k = (long long)key[r];
            bool c = (k > last) & (k < best);
            best = c ? k : best;
        }
#pragma unroll
        for (int off = 32; off; off >>= 1) {
            long long o = __shfl_xor(best, off);
            best = (o < best) ? o : best;
        }
        last = best;
        mykey = (lane == sel) ? best : mykey;
    }
    if (lane < NK) {
        int g = row * NK + lane;
        int j = (int)((unsigned long long)mykey & 0xffffffffULL);
        dnb[g]    = __uint_as_float((unsigned)((unsigned long long)mykey >> 32));
        eidx[g]   = j;
        eidx_f[g] = (float)j;
    }
}

// ---------------- kernel 2: features(f16) + MFMA GEMM + LayerNorm ----------------
__global__ __launch_bounds__(256) void k_edge(const float* __restrict__ atoms5,
                                              const int*   __restrict__ eidx,
                                              const float* __restrict__ dnb,
                                              const int*   __restrict__ ridx,
                                              const int*   __restrict__ chl,
                                              const float* __restrict__ posW,
                                              const float* __restrict__ posb,
                                              const _Float16* __restrict__ Wt,
                                              const float* __restrict__ lns,
                                              const float* __restrict__ lno,
                                              float* __restrict__ Eout)
{
    __shared__ __align__(16) _Float16 fA[BM][424];
    int t = threadIdx.x;
    int base = blockIdx.x * BM;

    // ---- phase 1: features. 4 threads per edge; thread q handles s = q*4..q*4+3
    {
        int e = t >> 2;
        int q = t & 3;
        int g = base + e;
        int b = g / (NL * NK);
        int rem = g - b * (NL * NK);
        int i = rem / NK;
        int gi = b * NL + i;
        int j = eidx[g];
        int gj = b * NL + j;

        int off = ridx[gi] - ridx[gj];
        int ec  = (chl[gi] == chl[gj]) ? 1 : 0;
        int dp  = min(max(off + 32, 0), 64);
        dp = ec ? dp : 65;
        half4 pv;
#pragma unroll
        for (int u = 0; u < 4; u++) {
            int s = q * 4 + u;
            pv[u] = (_Float16)(posW[dp * 16 + s] + posb[s]);
        }
        *(half4*)&fA[e][q * 4] = pv;

        const float* Ai = atoms5 + (size_t)gi * 15;
        const float* Aj = atoms5 + (size_t)gj * 15;
        float D[25];
        D[0] = dnb[g];
#pragma unroll
        for (int p = 0; p < 24; p++) {
            const float* a  = Ai + c_PA[p] * 3;
            const float* bb = Aj + c_PB[p] * 3;
            float dx = a[0]-bb[0], dy = a[1]-bb[1], dz = a[2]-bb[2];
            D[p+1] = sqrtf(dx*dx + dy*dy + dz*dz + 1e-6f);
        }
        float mu0 = 2.0f + (float)(q * 4) * (20.0f / 15.0f);
#pragma unroll
        for (int p = 0; p < 25; p++) {
            half4 rv;
#pragma unroll
            for (int u = 0; u < 4; u++) {
                float mu = mu0 + (float)u * (20.0f / 15.0f);
                float z = (D[p] - mu) * 0.8f;
                rv[u] = (_Float16)__expf(-(z * z));
            }
            *(half4*)&fA[e][16 + p * 16 + q * 4] = rv;
        }
    }
    __syncthreads();

    // ---- phase 2: MFMA GEMM
    int w    = t >> 6;
    int lane = t & 63;
    int l16  = lane & 15;
    int g8   = (lane >> 4) * 8;

    f32x4 acc[8];
#pragma unroll
    for (int nt = 0; nt < 8; nt++) acc[nt] = (f32x4){0.f, 0.f, 0.f, 0.f};

    const _Float16* fArow = &fA[w * 16 + l16][0];
    const _Float16* wtb   = Wt + (size_t)l16 * NEIN + g8;

    for (int kt = 0; kt < 13; kt++) {
        half8 a = *(const half8*)(fArow + kt * 32 + g8);
#pragma unroll
        for (int nt = 0; nt < 8; nt++) {
            half8 bf = *(const half8*)(wtb + (size_t)nt * 16 * NEIN + kt * 32);
            acc[nt] = __builtin_amdgcn_mfma_f32_16x16x32_f16(a, bf, acc[nt], 0, 0, 0);
        }
    }

    // ---- phase 3: LayerNorm. Row (lane>>4)*4+r lives in one 16-lane group.
    float sum[4], ssq[4];
#pragma unroll
    for (int r = 0; r < 4; r++) { sum[r] = 0.f; ssq[r] = 0.f; }
#pragma unroll
    for (int nt = 0; nt < 8; nt++)
#pragma unroll
        for (int r = 0; r < 4; r++) {
            float v = acc[nt][r];
            sum[r] += v;
            ssq[r] += v * v;
        }
#pragma unroll
    for (int off = 1; off < 16; off <<= 1)
#pragma unroll
        for (int r = 0; r < 4; r++) {
            sum[r] += __shfl_xor(sum[r], off);
            ssq[r] += __shfl_xor(ssq[r], off);
        }

    float sc[8], of[8];
#pragma unroll
    for (int nt = 0; nt < 8; nt++) {
        sc[nt] = lns[nt * 16 + l16];
        of[nt] = lno[nt * 16 + l16];
    }
#pragma unroll
    for (int r = 0; r < 4; r++) {
        float mu  = sum[r] * (1.0f / 128.0f);
        float var = ssq[r] * (1.0f / 128.0f) - mu * mu;
        float rs  = 1.0f / sqrtf(var + 1e-5f);
        int edge  = base + w * 16 + (lane >> 4) * 4 + r;
        float* op = Eout + (size_t)edge * NEF + l16;
#pragma unroll
        for (int nt = 0; nt < 8; nt++)
            op[nt * 16] = sc[nt] * ((acc[nt][r] - mu) * rs) + of[nt];
    }
}

extern "C" void kernel_launch(void* const* d_in, const int* in_sizes, int n_in,
                              void* d_out, int out_size, void* d_ws, size_t ws_size,
                              hipStream_t stream)
{
    const float* X    = (const float*)d_in[0];
    const float* mask = (const float*)d_in[1];
    const int*   ridx = (const int*)d_in[2];
    const int*   chl  = (const int*)d_in[3];
    const float* posW = (const float*)d_in[4];
    const float* posb = (const float*)d_in[5];
    const float* eW   = (const float*)d_in[6];
    const float* lns  = (const float*)d_in[7];
    const float* lno  = (const float*)d_in[8];

    float* Eout   = (float*)d_out;                                  // B*L*K*128
    float* eidx_f = Eout + (size_t)NB * NL * NK * NEF;              // B*L*K (as float)

    char* ws = (char*)d_ws;
    float*    atoms5 = (float*)ws;                                  // 4096*15 f32
    float*    dnb    = (float*)(ws + 245760);                       // 122880 f32
    int*      eidx   = (int*)(ws + 737280);                         // 122880 i32
    _Float16* Wt     = (_Float16*)(ws + 1228800);                   // 128*416 f16
    float4*   caw4   = (float4*)(ws + 1335296);                     // 4096 float4

    k_atoms<<<(NB * NL + 255) / 256, 256, 0, stream>>>(X, mask, atoms5, caw4);
    k_wconv<<<(NEIN * NEF + 255) / 256, 256, 0, stream>>>(eW, Wt);
    k_topk<<<(NB * NL) / 4, 256, 0, stream>>>(caw4, dnb, eidx, eidx_f);
    k_edge<<<(NB * NL * NK) / BM, 256, 0, stream>>>(atoms5, eidx, dnb, ridx, chl,
                                                    posW, posb, Wt, lns, lno, Eout);
}